// Round 5
// baseline (89.562 us; speedup 1.0000x reference)
//
#include <hip/hip_runtime.h>
#include <math.h>

#define LOG2E 1.44269504088896340736f
typedef float v2f __attribute__((ext_vector_type(2)));

// ws layout:
//   ctx   [32][2][768]  : scene_context | speaker_context
//   final [32][3840]    : [z(2304) | sent_sh(512) | scene_sh(512) | spkr_sh(512)]
//   hpart [32][8][256]  : mlp stage-1 K-split partials

// K1: small attentions (y<48: 2 parts x 24 rowgroups of 32) + sentence projection
// (y=48,49: two 256-col halves). 256 threads.
__global__ __launch_bounds__(256) void k1_small_attn_proj0(
    const float* __restrict__ sentence,
    const float* __restrict__ target,
    const float* __restrict__ other,
    const float* __restrict__ scene_desc,
    const float* __restrict__ scene_sent,
    const float* __restrict__ Ws,   // [768, 512]
    const float* __restrict__ bs,   // [512]
    float* __restrict__ ctx,
    float* __restrict__ final_)
{
    const int b = blockIdx.x;
    const int y = blockIdx.y;
    const int tid = threadIdx.x;
    __shared__ float s0[768];
    __shared__ float s1[768];

    if (y < 48) {
        const int part = y / 24;       // 0: scene ctx, 1: speaker ctx
        const int rg = y - part * 24;
        const float* qp; const float* kp; const float* vp;
        if (part == 0) { qp = scene_sent + b * 768; kp = qp;              vp = scene_desc + b * 768; }
        else           { qp = other + b * 768;      kp = target + b * 768; vp = kp; }
        for (int i = tid; i < 768; i += 256) { s0[i] = kp[i]; s1[i] = vp[i]; }
        __syncthreads();

        const int r   = rg * 32 + (tid >> 3);
        const int sub = tid & 7;
        const float qL = qp[r] * LOG2E;
        const v2f qL2 = {qL, qL};
        const float4* __restrict__ kv = (const float4*)s0;  // 192 float4
        const float4* __restrict__ vv = (const float4*)s1;
        v2f n01 = {0.f, 0.f}, n23 = {0.f, 0.f}, d01 = {0.f, 0.f}, d23 = {0.f, 0.f};
        #pragma unroll 4
        for (int i = 0; i < 24; ++i) {
            const int j = sub + 8 * i;
            const float4 k4 = kv[j];
            const float4 v4 = vv[j];
            const v2f ka = {k4.x, k4.y}, kb = {k4.z, k4.w};
            const v2f va = {v4.x, v4.y}, vbv = {v4.z, v4.w};
            const v2f xa = qL2 * ka, xb = qL2 * kb;
            const v2f ea = {__builtin_amdgcn_exp2f(xa.x), __builtin_amdgcn_exp2f(xa.y)};
            const v2f eb = {__builtin_amdgcn_exp2f(xb.x), __builtin_amdgcn_exp2f(xb.y)};
            n01 += ea * va;  d01 += ea;
            n23 += eb * vbv; d23 += eb;
        }
        float num = (n01.x + n01.y) + (n23.x + n23.y);
        float den = (d01.x + d01.y) + (d23.x + d23.y);
        num += __shfl_xor(num, 1, 64); num += __shfl_xor(num, 2, 64); num += __shfl_xor(num, 4, 64);
        den += __shfl_xor(den, 1, 64); den += __shfl_xor(den, 2, 64); den += __shfl_xor(den, 4, 64);
        if (sub == 0)
            ctx[b * 1536 + part * 768 + r] = num / den;
    } else {
        const int col = (y - 48) * 256 + tid;     // 0..511
        for (int i = tid; i < 768; i += 256) s0[i] = sentence[b * 768 + i];
        __syncthreads();
        float acc = bs[col];
        #pragma unroll 8
        for (int k = 0; k < 768; ++k)
            acc += s0[k] * Ws[k * 512 + col];
        final_[b * 3840 + 2304 + col] = acc;
    }
}

// K2: fused self-attention over f=[sentence|ctx] (y<72: rowgroups of 32) +
// ctx projections (y=72..75: p in {1,2} x two 256-col halves). 256 threads.
__global__ __launch_bounds__(256) void k2_fused_attn_proj12(
    const float* __restrict__ sentence,
    const float* __restrict__ ctx,
    const float* __restrict__ Ws,
    const float* __restrict__ bs,
    float* __restrict__ final_)
{
    const int b = blockIdx.x;
    const int y = blockIdx.y;
    const int tid = threadIdx.x;
    __shared__ float vb[2304];

    if (y < 72) {
        for (int i = tid; i < 2304; i += 256)
            vb[i] = (i < 768) ? sentence[b * 768 + i] : ctx[b * 1536 + (i - 768)];
        __syncthreads();

        const int r   = y * 32 + (tid >> 3);
        const int sub = tid & 7;
        const float qL = vb[r] * LOG2E;
        const v2f qL2 = {qL, qL};
        const float4* __restrict__ fv = (const float4*)vb;  // 576 float4
        v2f n01 = {0.f, 0.f}, n23 = {0.f, 0.f}, d01 = {0.f, 0.f}, d23 = {0.f, 0.f};
        #pragma unroll 4
        for (int i = 0; i < 72; ++i) {
            const int j = sub + 8 * i;
            const float4 f4 = fv[j];
            const v2f fa = {f4.x, f4.y}, fb = {f4.z, f4.w};
            const v2f xa = qL2 * fa, xb = qL2 * fb;
            const v2f ea = {__builtin_amdgcn_exp2f(xa.x), __builtin_amdgcn_exp2f(xa.y)};
            const v2f eb = {__builtin_amdgcn_exp2f(xb.x), __builtin_amdgcn_exp2f(xb.y)};
            n01 += ea * fa; d01 += ea;
            n23 += eb * fb; d23 += eb;
        }
        float num = (n01.x + n01.y) + (n23.x + n23.y);
        float den = (d01.x + d01.y) + (d23.x + d23.y);
        num += __shfl_xor(num, 1, 64); num += __shfl_xor(num, 2, 64); num += __shfl_xor(num, 4, 64);
        den += __shfl_xor(den, 1, 64); den += __shfl_xor(den, 2, 64); den += __shfl_xor(den, 4, 64);
        if (sub == 0)
            final_[b * 3840 + r] = num / den;
    } else {
        const int idx  = y - 72;
        const int p    = 1 + (idx >> 1);          // 1 or 2
        const int col  = (idx & 1) * 256 + tid;   // 0..511
        for (int i = tid; i < 768; i += 256) vb[i] = ctx[b * 1536 + (p - 1) * 768 + i];
        __syncthreads();
        float acc = bs[col];
        #pragma unroll 8
        for (int k = 0; k < 768; ++k)
            acc += vb[k] * Ws[k * 512 + col];
        final_[b * 3840 + 2304 + p * 512 + col] = acc;
    }
}

// MLP stage 1, K-split across blocks: grid (32,8), 1024 threads.
__global__ __launch_bounds__(1024) void mlp_part_kernel(
    const float* __restrict__ final_,
    const float* __restrict__ W1,   // [3840, 256]
    float* __restrict__ hpart)      // [32][8][256]
{
    const int b = blockIdx.x;
    const int c = blockIdx.y;
    const int tid = threadIdx.x;
    const int base = c * 480;

    __shared__ float fb[480];
    __shared__ float red[16][256];
    if (tid < 480) fb[tid] = final_[b * 3840 + base + tid];
    __syncthreads();

    const int g = tid >> 6;         // wave id, 16 waves
    const int q = tid & 63;         // column quad
    const float4* __restrict__ Wv = (const float4*)W1;   // [3840][64]
    float ax = 0.f, ay = 0.f, az = 0.f, aw = 0.f;
    const int l0 = g * 30;
    #pragma unroll 5
    for (int kk = 0; kk < 30; ++kk) {
        const float xv = fb[l0 + kk];
        const float4 w = Wv[(base + l0 + kk) * 64 + q];
        ax += xv * w.x; ay += xv * w.y; az += xv * w.z; aw += xv * w.w;
    }
    red[g][q * 4 + 0] = ax;
    red[g][q * 4 + 1] = ay;
    red[g][q * 4 + 2] = az;
    red[g][q * 4 + 3] = aw;
    __syncthreads();

    if (tid < 256) {
        float s = 0.f;
        #pragma unroll
        for (int g2 = 0; g2 < 16; ++g2) s += red[g2][tid];
        hpart[(b * 8 + c) * 256 + tid] = s;
    }
}

// MLP tail: combine K-partials, relu, [256x7] head, sigmoid. grid 32, 512 threads.
__global__ __launch_bounds__(512) void mlp_tail_kernel(
    const float* __restrict__ hpart,
    const float* __restrict__ b1,
    const float* __restrict__ W2,   // [256, 7]
    const float* __restrict__ b2,
    float* __restrict__ out)        // [32, 7]
{
    const int b = blockIdx.x;
    const int tid = threadIdx.x;

    __shared__ float hb[256];
    if (tid < 256) {
        float s = b1[tid];
        #pragma unroll
        for (int c = 0; c < 8; ++c) s += hpart[(b * 8 + c) * 256 + tid];
        hb[tid] = fmaxf(s, 0.f);
    }
    __syncthreads();

    const int w = tid >> 6;
    const int lane = tid & 63;
    if (w < 7) {
        float a = 0.f;
        #pragma unroll
        for (int c = lane; c < 256; c += 64)
            a += hb[c] * W2[c * 7 + w];
        #pragma unroll
        for (int off = 32; off > 0; off >>= 1)
            a += __shfl_down(a, off, 64);
        if (lane == 0)
            out[b * 7 + w] = 1.f / (1.f + __expf(-(a + b2[w])));
    }
}

extern "C" void kernel_launch(void* const* d_in, const int* in_sizes, int n_in,
                              void* d_out, int out_size, void* d_ws, size_t ws_size,
                              hipStream_t stream) {
    const float* sentence   = (const float*)d_in[0];
    const float* target     = (const float*)d_in[1];
    const float* other      = (const float*)d_in[2];
    const float* scene_desc = (const float*)d_in[3];
    const float* scene_sent = (const float*)d_in[4];
    const float* Ws         = (const float*)d_in[5];
    const float* bs         = (const float*)d_in[6];
    const float* W1         = (const float*)d_in[7];
    const float* b1         = (const float*)d_in[8];
    const float* W2         = (const float*)d_in[9];
    const float* b2         = (const float*)d_in[10];
    float* out = (float*)d_out;

    float* ctx    = (float*)d_ws;             // 32*1536 floats
    float* final_ = ctx + 32 * 1536;          // 32*3840 floats
    float* hpart  = final_ + 32 * 3840;       // 32*8*256 floats

    k1_small_attn_proj0<<<dim3(32, 50), 256, 0, stream>>>(sentence, target, other,
                                                          scene_desc, scene_sent,
                                                          Ws, bs, ctx, final_);
    k2_fused_attn_proj12<<<dim3(32, 76), 256, 0, stream>>>(sentence, ctx, Ws, bs, final_);
    mlp_part_kernel<<<dim3(32, 8), 1024, 0, stream>>>(final_, W1, hpart);
    mlp_tail_kernel<<<32, 512, 0, stream>>>(hpart, b1, W2, b2, out);
}

// Round 6
// 61.101 us; speedup vs baseline: 1.4658x; 1.4658x over previous
//
#include <hip/hip_runtime.h>
#include <math.h>

#define LOG2E 1.44269504088896340736f
typedef float v2f __attribute__((ext_vector_type(2)));

// ws layout:
//   ctx   [32][2][768]  : scene_context | speaker_context
//   final [32][3840]    : [z(2304) | sent_sh(512) | scene_sh(512) | spkr_sh(512)]
//   hpart [32][8][256]  : mlp stage-1 K-split partials

// ---- shared proj helper: y-slice of [768]x[768,512] with 512 threads, 4-way K-split
__device__ __forceinline__ void proj_512(
    const float* __restrict__ xsrc,          // [768] input (global)
    const float* __restrict__ Ws,            // [768, 512]
    const float* __restrict__ bs,            // [512]
    float* __restrict__ dst,                 // [512] output (global)
    float* xb,                               // LDS [768]
    float (*red)[512],                       // LDS [4][512]
    int tid)
{
    if (tid < 512) { xb[tid] = xsrc[tid]; }
    if (tid >= 256) { xb[tid + 256] = xsrc[tid + 256]; }
    __syncthreads();

    const int g = tid >> 7;        // 0..3
    const int q = tid & 127;       // column quad
    const float4* __restrict__ Wv = (const float4*)Ws;   // [768][128]
    float ax = 0.f, ay = 0.f, az = 0.f, aw = 0.f;
    #pragma unroll 8
    for (int k = g; k < 768; k += 4) {
        const float xv = xb[k];
        const float4 w = Wv[k * 128 + q];
        ax += xv * w.x; ay += xv * w.y; az += xv * w.z; aw += xv * w.w;
    }
    red[g][q * 4 + 0] = ax;
    red[g][q * 4 + 1] = ay;
    red[g][q * 4 + 2] = az;
    red[g][q * 4 + 3] = aw;
    __syncthreads();

    if (tid < 512) {
        float s = bs[tid] + red[0][tid] + red[1][tid] + red[2][tid] + red[3][tid];
        dst[tid] = s;
    }
}

// K1: small attentions (y<24: 2 parts x 12 rowgroups of 64) + sentence projection (y=24).
// 512 threads.
__global__ __launch_bounds__(512) void k1_small_attn_proj0(
    const float* __restrict__ sentence,
    const float* __restrict__ target,
    const float* __restrict__ other,
    const float* __restrict__ scene_desc,
    const float* __restrict__ scene_sent,
    const float* __restrict__ Ws,
    const float* __restrict__ bs,
    float* __restrict__ ctx,
    float* __restrict__ final_)
{
    const int b = blockIdx.x;
    const int y = blockIdx.y;
    const int tid = threadIdx.x;
    __shared__ float s0[768];
    __shared__ float s1[768];
    __shared__ float red[4][512];

    if (y < 24) {
        const int part = y / 12;       // 0: scene ctx, 1: speaker ctx
        const int rg = y - part * 12;
        const float* qp; const float* kp; const float* vp;
        if (part == 0) { qp = scene_sent + b * 768; kp = qp;               vp = scene_desc + b * 768; }
        else           { qp = other + b * 768;      kp = target + b * 768; vp = kp; }
        for (int i = tid; i < 768; i += 512) { s0[i] = kp[i]; s1[i] = vp[i]; }
        __syncthreads();

        const int r   = rg * 64 + (tid >> 3);
        const int sub = tid & 7;
        const float qL = qp[r] * LOG2E;
        const v2f qL2 = {qL, qL};
        const float4* __restrict__ kv = (const float4*)s0;  // 192 float4
        const float4* __restrict__ vv = (const float4*)s1;
        v2f n01 = {0.f, 0.f}, n23 = {0.f, 0.f}, d01 = {0.f, 0.f}, d23 = {0.f, 0.f};
        #pragma unroll 4
        for (int i = 0; i < 24; ++i) {
            const int j = sub + 8 * i;
            const float4 k4 = kv[j];
            const float4 v4 = vv[j];
            const v2f ka = {k4.x, k4.y}, kb = {k4.z, k4.w};
            const v2f va = {v4.x, v4.y}, vbv = {v4.z, v4.w};
            const v2f xa = qL2 * ka, xb2 = qL2 * kb;
            const v2f ea = {__builtin_amdgcn_exp2f(xa.x), __builtin_amdgcn_exp2f(xa.y)};
            const v2f eb = {__builtin_amdgcn_exp2f(xb2.x), __builtin_amdgcn_exp2f(xb2.y)};
            n01 += ea * va;  d01 += ea;
            n23 += eb * vbv; d23 += eb;
        }
        float num = (n01.x + n01.y) + (n23.x + n23.y);
        float den = (d01.x + d01.y) + (d23.x + d23.y);
        num += __shfl_xor(num, 1, 64); num += __shfl_xor(num, 2, 64); num += __shfl_xor(num, 4, 64);
        den += __shfl_xor(den, 1, 64); den += __shfl_xor(den, 2, 64); den += __shfl_xor(den, 4, 64);
        if (sub == 0)
            ctx[b * 1536 + part * 768 + r] = num / den;
    } else {
        proj_512(sentence + b * 768, Ws, bs, final_ + b * 3840 + 2304, s0, red, tid);
    }
}

// K2: fused self-attention over f=[sentence|ctx] (y<36: rowgroups of 64) +
// ctx projections (y=36,37). 512 threads.
__global__ __launch_bounds__(512) void k2_fused_attn_proj12(
    const float* __restrict__ sentence,
    const float* __restrict__ ctx,
    const float* __restrict__ Ws,
    const float* __restrict__ bs,
    float* __restrict__ final_)
{
    const int b = blockIdx.x;
    const int y = blockIdx.y;
    const int tid = threadIdx.x;
    __shared__ float vb[2304];
    __shared__ float red[4][512];

    if (y < 36) {
        for (int i = tid; i < 2304; i += 512)
            vb[i] = (i < 768) ? sentence[b * 768 + i] : ctx[b * 1536 + (i - 768)];
        __syncthreads();

        const int r   = y * 64 + (tid >> 3);
        const int sub = tid & 7;
        const float qL = vb[r] * LOG2E;
        const v2f qL2 = {qL, qL};
        const float4* __restrict__ fv = (const float4*)vb;  // 576 float4
        v2f n01 = {0.f, 0.f}, n23 = {0.f, 0.f}, d01 = {0.f, 0.f}, d23 = {0.f, 0.f};
        #pragma unroll 4
        for (int i = 0; i < 72; ++i) {
            const int j = sub + 8 * i;
            const float4 f4 = fv[j];
            const v2f fa = {f4.x, f4.y}, fb = {f4.z, f4.w};
            const v2f xa = qL2 * fa, xb2 = qL2 * fb;
            const v2f ea = {__builtin_amdgcn_exp2f(xa.x), __builtin_amdgcn_exp2f(xa.y)};
            const v2f eb = {__builtin_amdgcn_exp2f(xb2.x), __builtin_amdgcn_exp2f(xb2.y)};
            n01 += ea * fa; d01 += ea;
            n23 += eb * fb; d23 += eb;
        }
        float num = (n01.x + n01.y) + (n23.x + n23.y);
        float den = (d01.x + d01.y) + (d23.x + d23.y);
        num += __shfl_xor(num, 1, 64); num += __shfl_xor(num, 2, 64); num += __shfl_xor(num, 4, 64);
        den += __shfl_xor(den, 1, 64); den += __shfl_xor(den, 2, 64); den += __shfl_xor(den, 4, 64);
        if (sub == 0)
            final_[b * 3840 + r] = num / den;
    } else {
        const int p = y - 35;          // 1 or 2
        proj_512(ctx + b * 1536 + (p - 1) * 768, Ws, bs,
                 final_ + b * 3840 + 2304 + p * 512, vb, red, tid);
    }
}

// MLP stage 1, K-split across blocks: grid (32,8), 1024 threads.
__global__ __launch_bounds__(1024) void mlp_part_kernel(
    const float* __restrict__ final_,
    const float* __restrict__ W1,   // [3840, 256]
    float* __restrict__ hpart)      // [32][8][256]
{
    const int b = blockIdx.x;
    const int c = blockIdx.y;
    const int tid = threadIdx.x;
    const int base = c * 480;

    __shared__ float fb[480];
    __shared__ float red[16][256];
    if (tid < 480) fb[tid] = final_[b * 3840 + base + tid];
    __syncthreads();

    const int g = tid >> 6;         // wave id, 16 waves
    const int q = tid & 63;         // column quad
    const float4* __restrict__ Wv = (const float4*)W1;   // [3840][64]
    float ax = 0.f, ay = 0.f, az = 0.f, aw = 0.f;
    const int l0 = g * 30;
    #pragma unroll 5
    for (int kk = 0; kk < 30; ++kk) {
        const float xv = fb[l0 + kk];
        const float4 w = Wv[(base + l0 + kk) * 64 + q];
        ax += xv * w.x; ay += xv * w.y; az += xv * w.z; aw += xv * w.w;
    }
    red[g][q * 4 + 0] = ax;
    red[g][q * 4 + 1] = ay;
    red[g][q * 4 + 2] = az;
    red[g][q * 4 + 3] = aw;
    __syncthreads();

    if (tid < 256) {
        float s = 0.f;
        #pragma unroll
        for (int g2 = 0; g2 < 16; ++g2) s += red[g2][tid];
        hpart[(b * 8 + c) * 256 + tid] = s;
    }
}

// MLP tail: combine K-partials, relu, [256x7] head, sigmoid. grid 32, 512 threads.
__global__ __launch_bounds__(512) void mlp_tail_kernel(
    const float* __restrict__ hpart,
    const float* __restrict__ b1,
    const float* __restrict__ W2,   // [256, 7]
    const float* __restrict__ b2,
    float* __restrict__ out)        // [32, 7]
{
    const int b = blockIdx.x;
    const int tid = threadIdx.x;

    __shared__ float hb[256];
    if (tid < 256) {
        float s = b1[tid];
        #pragma unroll
        for (int c = 0; c < 8; ++c) s += hpart[(b * 8 + c) * 256 + tid];
        hb[tid] = fmaxf(s, 0.f);
    }
    __syncthreads();

    const int w = tid >> 6;
    const int lane = tid & 63;
    if (w < 7) {
        float a = 0.f;
        #pragma unroll
        for (int c = lane; c < 256; c += 64)
            a += hb[c] * W2[c * 7 + w];
        #pragma unroll
        for (int off = 32; off > 0; off >>= 1)
            a += __shfl_down(a, off, 64);
        if (lane == 0)
            out[b * 7 + w] = 1.f / (1.f + __expf(-(a + b2[w])));
    }
}

extern "C" void kernel_launch(void* const* d_in, const int* in_sizes, int n_in,
                              void* d_out, int out_size, void* d_ws, size_t ws_size,
                              hipStream_t stream) {
    const float* sentence   = (const float*)d_in[0];
    const float* target     = (const float*)d_in[1];
    const float* other      = (const float*)d_in[2];
    const float* scene_desc = (const float*)d_in[3];
    const float* scene_sent = (const float*)d_in[4];
    const float* Ws         = (const float*)d_in[5];
    const float* bs         = (const float*)d_in[6];
    const float* W1         = (const float*)d_in[7];
    const float* b1         = (const float*)d_in[8];
    const float* W2         = (const float*)d_in[9];
    const float* b2         = (const float*)d_in[10];
    float* out = (float*)d_out;

    float* ctx    = (float*)d_ws;             // 32*1536 floats
    float* final_ = ctx + 32 * 1536;          // 32*3840 floats
    float* hpart  = final_ + 32 * 3840;       // 32*8*256 floats

    k1_small_attn_proj0<<<dim3(32, 25), 512, 0, stream>>>(sentence, target, other,
                                                          scene_desc, scene_sent,
                                                          Ws, bs, ctx, final_);
    k2_fused_attn_proj12<<<dim3(32, 38), 512, 0, stream>>>(sentence, ctx, Ws, bs, final_);
    mlp_part_kernel<<<dim3(32, 8), 1024, 0, stream>>>(final_, W1, hpart);
    mlp_tail_kernel<<<32, 512, 0, stream>>>(hpart, b1, W2, b2, out);
}

// Round 7
// 58.224 us; speedup vs baseline: 1.5382x; 1.0494x over previous
//
#include <hip/hip_runtime.h>
#include <math.h>

#define LOG2E 1.44269504088896340736f
typedef float v2f __attribute__((ext_vector_type(2)));

// ws layout:
//   ctx   [32][2][768]  : scene_context | speaker_context
//   final [32][3840]    : [z(2304) | sent_sh(512) | scene_sh(512) | spkr_sh(512)]
//   hpart [32][8][256]  : mlp stage-1 K-split partials

// ---- shared proj helper: [768]x[768,512] with 512 threads, 4-way K-split
__device__ __forceinline__ void proj_512(
    const float* __restrict__ xsrc,
    const float* __restrict__ Ws,            // [768, 512]
    const float* __restrict__ bs,            // [512]
    float* __restrict__ dst,
    float* xb,                               // LDS [768]
    float (*red)[512],                       // LDS [4][512]
    int tid)
{
    if (tid < 512) { xb[tid] = xsrc[tid]; }
    if (tid >= 256) { xb[tid + 256] = xsrc[tid + 256]; }
    __syncthreads();

    const int g = tid >> 7;        // 0..3
    const int q = tid & 127;       // column quad
    const float4* __restrict__ Wv = (const float4*)Ws;   // [768][128]
    float ax = 0.f, ay = 0.f, az = 0.f, aw = 0.f;
    #pragma unroll 8
    for (int k = g; k < 768; k += 4) {
        const float xv = xb[k];
        const float4 w = Wv[k * 128 + q];
        ax += xv * w.x; ay += xv * w.y; az += xv * w.z; aw += xv * w.w;
    }
    red[g][q * 4 + 0] = ax;
    red[g][q * 4 + 1] = ay;
    red[g][q * 4 + 2] = az;
    red[g][q * 4 + 3] = aw;
    __syncthreads();

    if (tid < 512) {
        dst[tid] = bs[tid] + red[0][tid] + red[1][tid] + red[2][tid] + red[3][tid];
    }
}

// K1: small attentions (y<12: 2 parts x 6 rowgroups of 128) + sentence projection (y=12).
// 512 threads; 8 sub-threads per row; 2 rows per thread (register row-tile).
__global__ __launch_bounds__(512) void k1_small_attn_proj0(
    const float* __restrict__ sentence,
    const float* __restrict__ target,
    const float* __restrict__ other,
    const float* __restrict__ scene_desc,
    const float* __restrict__ scene_sent,
    const float* __restrict__ Ws,
    const float* __restrict__ bs,
    float* __restrict__ ctx,
    float* __restrict__ final_)
{
    const int b = blockIdx.x;
    const int y = blockIdx.y;
    const int tid = threadIdx.x;
    __shared__ float s0[768];
    __shared__ float s1[768];
    __shared__ float red[4][512];

    if (y < 12) {
        const int part = y / 6;        // 0: scene ctx, 1: speaker ctx
        const int rg = y - part * 6;
        const float* qp; const float* kp; const float* vp;
        if (part == 0) { qp = scene_sent + b * 768; kp = qp;               vp = scene_desc + b * 768; }
        else           { qp = other + b * 768;      kp = target + b * 768; vp = kp; }
        for (int i = tid; i < 768; i += 512) { s0[i] = kp[i]; s1[i] = vp[i]; }
        __syncthreads();

        const int r0  = rg * 128 + (tid >> 3);
        const int r1  = r0 + 64;
        const int sub = tid & 7;
        const float qA = qp[r0] * LOG2E;
        const float qB = qp[r1] * LOG2E;
        const v2f qA2 = {qA, qA}, qB2 = {qB, qB};
        const float4* __restrict__ kv = (const float4*)s0;  // 192 float4
        const float4* __restrict__ vv = (const float4*)s1;
        v2f nA0 = {0.f,0.f}, nA1 = {0.f,0.f}, dA0 = {0.f,0.f}, dA1 = {0.f,0.f};
        v2f nB0 = {0.f,0.f}, nB1 = {0.f,0.f}, dB0 = {0.f,0.f}, dB1 = {0.f,0.f};
        #pragma unroll 4
        for (int i = 0; i < 24; ++i) {
            const int j = sub + 8 * i;
            const float4 k4 = kv[j];
            const float4 v4 = vv[j];
            const v2f ka = {k4.x, k4.y}, kb = {k4.z, k4.w};
            const v2f va = {v4.x, v4.y}, vb2 = {v4.z, v4.w};
            const v2f xaA = qA2 * ka, xbA = qA2 * kb;
            const v2f eaA = {__builtin_amdgcn_exp2f(xaA.x), __builtin_amdgcn_exp2f(xaA.y)};
            const v2f ebA = {__builtin_amdgcn_exp2f(xbA.x), __builtin_amdgcn_exp2f(xbA.y)};
            nA0 += eaA * va;  dA0 += eaA;
            nA1 += ebA * vb2; dA1 += ebA;
            const v2f xaB = qB2 * ka, xbB = qB2 * kb;
            const v2f eaB = {__builtin_amdgcn_exp2f(xaB.x), __builtin_amdgcn_exp2f(xaB.y)};
            const v2f ebB = {__builtin_amdgcn_exp2f(xbB.x), __builtin_amdgcn_exp2f(xbB.y)};
            nB0 += eaB * va;  dB0 += eaB;
            nB1 += ebB * vb2; dB1 += ebB;
        }
        float numA = (nA0.x + nA0.y) + (nA1.x + nA1.y);
        float denA = (dA0.x + dA0.y) + (dA1.x + dA1.y);
        float numB = (nB0.x + nB0.y) + (nB1.x + nB1.y);
        float denB = (dB0.x + dB0.y) + (dB1.x + dB1.y);
        numA += __shfl_xor(numA, 1, 64); numA += __shfl_xor(numA, 2, 64); numA += __shfl_xor(numA, 4, 64);
        denA += __shfl_xor(denA, 1, 64); denA += __shfl_xor(denA, 2, 64); denA += __shfl_xor(denA, 4, 64);
        numB += __shfl_xor(numB, 1, 64); numB += __shfl_xor(numB, 2, 64); numB += __shfl_xor(numB, 4, 64);
        denB += __shfl_xor(denB, 1, 64); denB += __shfl_xor(denB, 2, 64); denB += __shfl_xor(denB, 4, 64);
        if (sub == 0) {
            ctx[b * 1536 + part * 768 + r0] = numA / denA;
            ctx[b * 1536 + part * 768 + r1] = numB / denB;
        }
    } else {
        proj_512(sentence + b * 768, Ws, bs, final_ + b * 3840 + 2304, s0, red, tid);
    }
}

// K2: fused self-attention over f=[sentence|ctx] (y<18: rowgroups of 128) +
// ctx projections (y=18,19). 512 threads; 8 subs; 2 rows/thread.
__global__ __launch_bounds__(512) void k2_fused_attn_proj12(
    const float* __restrict__ sentence,
    const float* __restrict__ ctx,
    const float* __restrict__ Ws,
    const float* __restrict__ bs,
    float* __restrict__ final_)
{
    const int b = blockIdx.x;
    const int y = blockIdx.y;
    const int tid = threadIdx.x;
    __shared__ float vb[2304];
    __shared__ float red[4][512];

    if (y < 18) {
        for (int i = tid; i < 2304; i += 512)
            vb[i] = (i < 768) ? sentence[b * 768 + i] : ctx[b * 1536 + (i - 768)];
        __syncthreads();

        const int r0  = y * 128 + (tid >> 3);
        const int r1  = r0 + 64;
        const int sub = tid & 7;
        const float qA = vb[r0] * LOG2E;
        const float qB = vb[r1] * LOG2E;
        const v2f qA2 = {qA, qA}, qB2 = {qB, qB};
        const float4* __restrict__ fv = (const float4*)vb;  // 576 float4
        v2f nA0 = {0.f,0.f}, nA1 = {0.f,0.f}, dA0 = {0.f,0.f}, dA1 = {0.f,0.f};
        v2f nB0 = {0.f,0.f}, nB1 = {0.f,0.f}, dB0 = {0.f,0.f}, dB1 = {0.f,0.f};
        #pragma unroll 4
        for (int i = 0; i < 72; ++i) {
            const int j = sub + 8 * i;
            const float4 f4 = fv[j];
            const v2f fa = {f4.x, f4.y}, fb = {f4.z, f4.w};
            const v2f xaA = qA2 * fa, xbA = qA2 * fb;
            const v2f eaA = {__builtin_amdgcn_exp2f(xaA.x), __builtin_amdgcn_exp2f(xaA.y)};
            const v2f ebA = {__builtin_amdgcn_exp2f(xbA.x), __builtin_amdgcn_exp2f(xbA.y)};
            nA0 += eaA * fa; dA0 += eaA;
            nA1 += ebA * fb; dA1 += ebA;
            const v2f xaB = qB2 * fa, xbB = qB2 * fb;
            const v2f eaB = {__builtin_amdgcn_exp2f(xaB.x), __builtin_amdgcn_exp2f(xaB.y)};
            const v2f ebB = {__builtin_amdgcn_exp2f(xbB.x), __builtin_amdgcn_exp2f(xbB.y)};
            nB0 += eaB * fa; dB0 += eaB;
            nB1 += ebB * fb; dB1 += ebB;
        }
        float numA = (nA0.x + nA0.y) + (nA1.x + nA1.y);
        float denA = (dA0.x + dA0.y) + (dA1.x + dA1.y);
        float numB = (nB0.x + nB0.y) + (nB1.x + nB1.y);
        float denB = (dB0.x + dB0.y) + (dB1.x + dB1.y);
        numA += __shfl_xor(numA, 1, 64); numA += __shfl_xor(numA, 2, 64); numA += __shfl_xor(numA, 4, 64);
        denA += __shfl_xor(denA, 1, 64); denA += __shfl_xor(denA, 2, 64); denA += __shfl_xor(denA, 4, 64);
        numB += __shfl_xor(numB, 1, 64); numB += __shfl_xor(numB, 2, 64); numB += __shfl_xor(numB, 4, 64);
        denB += __shfl_xor(denB, 1, 64); denB += __shfl_xor(denB, 2, 64); denB += __shfl_xor(denB, 4, 64);
        if (sub == 0) {
            final_[b * 3840 + r0] = numA / denA;
            final_[b * 3840 + r1] = numB / denB;
        }
    } else {
        const int p = y - 17;          // 1 or 2
        proj_512(ctx + b * 1536 + (p - 1) * 768, Ws, bs,
                 final_ + b * 3840 + 2304 + p * 512, vb, red, tid);
    }
}

// MLP stage 1, K-split across blocks: grid (32,8), 1024 threads.
__global__ __launch_bounds__(1024) void mlp_part_kernel(
    const float* __restrict__ final_,
    const float* __restrict__ W1,   // [3840, 256]
    float* __restrict__ hpart)      // [32][8][256]
{
    const int b = blockIdx.x;
    const int c = blockIdx.y;
    const int tid = threadIdx.x;
    const int base = c * 480;

    __shared__ float fb[480];
    __shared__ float red[16][256];
    if (tid < 480) fb[tid] = final_[b * 3840 + base + tid];
    __syncthreads();

    const int g = tid >> 6;         // wave id, 16 waves
    const int q = tid & 63;         // column quad
    const float4* __restrict__ Wv = (const float4*)W1;   // [3840][64]
    float ax = 0.f, ay = 0.f, az = 0.f, aw = 0.f;
    const int l0 = g * 30;
    #pragma unroll 5
    for (int kk = 0; kk < 30; ++kk) {
        const float xv = fb[l0 + kk];
        const float4 w = Wv[(base + l0 + kk) * 64 + q];
        ax += xv * w.x; ay += xv * w.y; az += xv * w.z; aw += xv * w.w;
    }
    red[g][q * 4 + 0] = ax;
    red[g][q * 4 + 1] = ay;
    red[g][q * 4 + 2] = az;
    red[g][q * 4 + 3] = aw;
    __syncthreads();

    if (tid < 256) {
        float s = 0.f;
        #pragma unroll
        for (int g2 = 0; g2 < 16; ++g2) s += red[g2][tid];
        hpart[(b * 8 + c) * 256 + tid] = s;
    }
}

// MLP tail: combine K-partials, relu, [256x7] head, sigmoid. grid 32, 512 threads.
__global__ __launch_bounds__(512) void mlp_tail_kernel(
    const float* __restrict__ hpart,
    const float* __restrict__ b1,
    const float* __restrict__ W2,   // [256, 7]
    const float* __restrict__ b2,
    float* __restrict__ out)        // [32, 7]
{
    const int b = blockIdx.x;
    const int tid = threadIdx.x;

    __shared__ float hb[256];
    if (tid < 256) {
        float s = b1[tid];
        #pragma unroll
        for (int c = 0; c < 8; ++c) s += hpart[(b * 8 + c) * 256 + tid];
        hb[tid] = fmaxf(s, 0.f);
    }
    __syncthreads();

    const int w = tid >> 6;
    const int lane = tid & 63;
    if (w < 7) {
        float a = 0.f;
        #pragma unroll
        for (int c = lane; c < 256; c += 64)
            a += hb[c] * W2[c * 7 + w];
        #pragma unroll
        for (int off = 32; off > 0; off >>= 1)
            a += __shfl_down(a, off, 64);
        if (lane == 0)
            out[b * 7 + w] = 1.f / (1.f + __expf(-(a + b2[w])));
    }
}

extern "C" void kernel_launch(void* const* d_in, const int* in_sizes, int n_in,
                              void* d_out, int out_size, void* d_ws, size_t ws_size,
                              hipStream_t stream) {
    const float* sentence   = (const float*)d_in[0];
    const float* target     = (const float*)d_in[1];
    const float* other      = (const float*)d_in[2];
    const float* scene_desc = (const float*)d_in[3];
    const float* scene_sent = (const float*)d_in[4];
    const float* Ws         = (const float*)d_in[5];
    const float* bs         = (const float*)d_in[6];
    const float* W1         = (const float*)d_in[7];
    const float* b1         = (const float*)d_in[8];
    const float* W2         = (const float*)d_in[9];
    const float* b2         = (const float*)d_in[10];
    float* out = (float*)d_out;

    float* ctx    = (float*)d_ws;             // 32*1536 floats
    float* final_ = ctx + 32 * 1536;          // 32*3840 floats
    float* hpart  = final_ + 32 * 3840;       // 32*8*256 floats

    k1_small_attn_proj0<<<dim3(32, 13), 512, 0, stream>>>(sentence, target, other,
                                                          scene_desc, scene_sent,
                                                          Ws, bs, ctx, final_);
    k2_fused_attn_proj12<<<dim3(32, 20), 512, 0, stream>>>(sentence, ctx, Ws, bs, final_);
    mlp_part_kernel<<<dim3(32, 8), 1024, 0, stream>>>(final_, W1, hpart);
    mlp_tail_kernel<<<32, 512, 0, stream>>>(hpart, b1, W2, b2, out);
}